// Round 2
// baseline (208.008 us; speedup 1.0000x reference)
//
#include <hip/hip_runtime.h>
#include <hip/hip_bf16.h>

// Problem constants
#define B_    2
#define S_    2048
#define DIM_  512
#define H_    8
#define HD_   64
#define TOUT_ 1536   // 2*QK + DIM
#define ROWS_ (B_ * S_)   // 4096

typedef unsigned short ushort_t;
typedef __attribute__((ext_vector_type(8))) __bf16 bf16x8;
typedef __attribute__((ext_vector_type(4))) float floatx4;

#define AS_GLB __attribute__((address_space(1)))
#define AS_LDS __attribute__((address_space(3)))

// ---------- numeric helpers ----------
__device__ __forceinline__ unsigned short f2bfu(float f) {
    unsigned u = __float_as_uint(f);
    unsigned r = (u + 0x7fffu + ((u >> 16) & 1u)) >> 16;
    return (unsigned short)r;
}
__device__ __forceinline__ bf16x8 cvt8(const float* p) {
    float4 a = *reinterpret_cast<const float4*>(p);
    float4 b = *reinterpret_cast<const float4*>(p + 4);
    ushort_t o[8] = {f2bfu(a.x), f2bfu(a.y), f2bfu(a.z), f2bfu(a.w),
                     f2bfu(b.x), f2bfu(b.y), f2bfu(b.z), f2bfu(b.w)};
    return *reinterpret_cast<bf16x8*>(o);
}

// ---------- fused mask classify + decode (single block) ----------
__global__ void tmha_mask(const unsigned char* mb, int* wm) {
    __shared__ int s_bf, s_f, s_u8;
    int tid = threadIdx.x;
    if (tid == 0) { s_bf = 0; s_f = 0; s_u8 = 0; }
    __syncthreads();
    int cbf = 0, cf = 0, cu8 = 0;
    for (int i = tid; i < 4096; i += 256) {
        unsigned char v = mb[i];
        if (v == 0x3F || v == 0x80) {
            cf++;
            if ((i & 3) == 1) cbf++;
        } else if (v != 0 && (i & 3) != 0) {
            cu8++;
        }
    }
    atomicAdd(&s_bf, cbf); atomicAdd(&s_f, cf); atomicAdd(&s_u8, cu8);
    __syncthreads();
    int cls = (s_bf > 0) ? 2 : (s_f > 0) ? 3 : (s_u8 > 0) ? 0 : 1;
    for (int i = tid; i < ROWS_; i += 256) {
        int v;
        if (cls == 0)      v = (mb[i] != 0);
        else if (cls == 1) v = (reinterpret_cast<const int*>(mb)[i] != 0);
        else if (cls == 2) v = ((reinterpret_cast<const unsigned short*>(mb)[i] & 0x7fffu) != 0);
        else               v = ((reinterpret_cast<const unsigned int*>(mb)[i] & 0x7fffffffu) != 0);
        wm[i] = v;
    }
}

// ---------- fused fp32 -> bf16 casts for x, Wt, Wo ----------
#define XN4_  (ROWS_ * DIM_ / 4)                  // 524288
#define WTN4_ (TOUT_ * DIM_ / 4)                  // 196608
#define WON4_ (DIM_ * DIM_ / 4)                   // 65536
__global__ __launch_bounds__(256) void cast3_bf16(const float* __restrict__ x,
                                                  const float* __restrict__ wt,
                                                  const float* __restrict__ wo,
                                                  ushort_t* __restrict__ xb,
                                                  ushort_t* __restrict__ wtb,
                                                  ushort_t* __restrict__ wob) {
    int i = blockIdx.x * 256 + threadIdx.x;
    const float* s; ushort_t* d; int off;
    if (i < XN4_)              { s = x;  d = xb;  off = i; }
    else if (i < XN4_ + WTN4_) { s = wt; d = wtb; off = i - XN4_; }
    else                       { s = wo; d = wob; off = i - XN4_ - WTN4_; }
    float4 v = reinterpret_cast<const float4*>(s)[off];
    ushort_t o[4] = {f2bfu(v.x), f2bfu(v.y), f2bfu(v.z), f2bfu(v.w)};
    reinterpret_cast<uint2*>(d)[off] = *reinterpret_cast<uint2*>(o);
}

// ==================================================================
// MFMA GEMM (proven R5): C[M,N] = A[M,K] @ B[N,K]^T, XOR-swizzled LDS.
// OUT_BF16: epilogue casts to bf16 (used for gemm1 -> t).
// ==================================================================
template <int TM, int N, int K, bool OUT_BF16>
__global__ __launch_bounds__(256) void mfma_gemm_bt(const ushort_t* __restrict__ A,
                                                    const ushort_t* __restrict__ Bm,
                                                    void* __restrict__ Cout) {
    constexpr int FM = (TM + 31) / 32;
    __shared__ __align__(16) ushort_t As[TM * 64];
    __shared__ __align__(16) ushort_t Bs[128 * 64];
    int tid = threadIdx.x;
    int lane = tid & 63;
    int wv = tid >> 6;
    int wm = wv >> 1, wn = wv & 1;
    int quad = lane >> 4;
    int mrow = lane & 15;
    int bx = blockIdx.x;
    int by = blockIdx.y;

    floatx4 acc[FM][4];
#pragma unroll
    for (int i = 0; i < FM; i++)
#pragma unroll
        for (int j = 0; j < 4; j++) acc[i][j] = (floatx4){0.f, 0.f, 0.f, 0.f};

    for (int k0 = 0; k0 < K; k0 += 64) {
#pragma unroll
        for (int t = 0; t < TM / 32; t++) {
            int p = (wv * (TM / 32) + t) * 64 + lane;
            int row = p >> 3, cp = p & 7;
            int gc = cp ^ (row & 7);
            const ushort_t* ga = A + (size_t)(by * TM + row) * K + k0 + gc * 8;
            __builtin_amdgcn_global_load_lds((const AS_GLB unsigned int*)ga,
                                             (AS_LDS unsigned int*)&As[(size_t)(wv * (TM / 32) + t) * 64 * 8],
                                             16, 0, 0);
        }
#pragma unroll
        for (int t = 0; t < 4; t++) {
            int p = (wv * 4 + t) * 64 + lane;
            int row = p >> 3, cp = p & 7;
            int gc = cp ^ (row & 7);
            const ushort_t* gb = Bm + (size_t)(bx * 128 + row) * K + k0 + gc * 8;
            __builtin_amdgcn_global_load_lds((const AS_GLB unsigned int*)gb,
                                             (AS_LDS unsigned int*)&Bs[(size_t)(wv * 4 + t) * 64 * 8],
                                             16, 0, 0);
        }
        __syncthreads();
#pragma unroll
        for (int ks = 0; ks < 64; ks += 32) {
            int c = (ks >> 3) + quad;
            bf16x8 af[FM], bf[4];
#pragma unroll
            for (int i = 0; i < FM; i++) {
                int row = wm * (TM / 2) + i * 16 + mrow;
                int pos = row * 8 + (c ^ (row & 7));
                af[i] = *reinterpret_cast<const bf16x8*>(&As[pos * 8]);
            }
#pragma unroll
            for (int j = 0; j < 4; j++) {
                int row = wn * 64 + j * 16 + mrow;
                int pos = row * 8 + (c ^ (row & 7));
                bf[j] = *reinterpret_cast<const bf16x8*>(&Bs[pos * 8]);
            }
#pragma unroll
            for (int i = 0; i < FM; i++)
#pragma unroll
                for (int j = 0; j < 4; j++)
                    acc[i][j] = __builtin_amdgcn_mfma_f32_16x16x32_bf16(af[i], bf[j], acc[i][j], 0, 0, 0);
        }
        __syncthreads();
    }

    int col0 = bx * 128 + wn * 64 + mrow;
    int row0 = by * TM + wm * (TM / 2) + quad * 4;
    if constexpr (OUT_BF16) {
        ushort_t* C = reinterpret_cast<ushort_t*>(Cout);
#pragma unroll
        for (int i = 0; i < FM; i++)
#pragma unroll
            for (int j = 0; j < 4; j++)
#pragma unroll
                for (int r = 0; r < 4; r++)
                    C[(size_t)(row0 + i * 16 + r) * N + col0 + j * 16] = f2bfu(acc[i][j][r]);
    } else {
        float* C = reinterpret_cast<float*>(Cout);
#pragma unroll
        for (int i = 0; i < FM; i++)
#pragma unroll
            for (int j = 0; j < 4; j++)
#pragma unroll
                for (int r = 0; r < 4; r++)
                    C[(size_t)(row0 + i * 16 + r) * N + col0 + j * 16] = acc[i][j][r];
    }
}

// ==================================================================
// MFMA rotation (proven R6, bf16 t input): per position s,
// out = in @ R_s^T if mask. One wave per s, no LDS, no barrier.
// ==================================================================
__global__ __launch_bounds__(256) void rot_qk_mfma(const ushort_t* __restrict__ t,
                                                   const float* __restrict__ rotG,
                                                   const int* __restrict__ wm,
                                                   ushort_t* __restrict__ Qb,
                                                   ushort_t* __restrict__ Kb) {
    int lane = threadIdx.x & 63;
    int wv = threadIdx.x >> 6;
    int row = blockIdx.x * 4 + wv;     // b*2048 + s
    int b = row >> 11, s = row & 2047;
    int lm = lane & 15, quad = lane >> 4;
    const ushort_t* trow = t + (size_t)row * TOUT_;

    if (wm[row]) {
        bf16x8 af[2];
#pragma unroll
        for (int kc = 0; kc < 2; kc++)
            af[kc] = *reinterpret_cast<const bf16x8*>(trow + lm * 64 + kc * 32 + quad * 8);

        const float* R = rotG + (size_t)row * 4096;
        floatx4 dacc[4];
#pragma unroll
        for (int nb = 0; nb < 4; nb++) dacc[nb] = (floatx4){0.f, 0.f, 0.f, 0.f};
#pragma unroll
        for (int nb = 0; nb < 4; nb++)
#pragma unroll
            for (int kc = 0; kc < 2; kc++) {
                bf16x8 bfr = cvt8(R + (size_t)(nb * 16 + lm) * 64 + kc * 32 + quad * 8);
                dacc[nb] = __builtin_amdgcn_mfma_f32_16x16x32_bf16(af[kc], bfr, dacc[nb], 0, 0, 0);
            }
#pragma unroll
        for (int nb = 0; nb < 4; nb++)
#pragma unroll
            for (int r = 0; r < 4; r++) {
                int vec = quad * 4 + r;
                int h = vec & 7;
                ushort_t* dst = (vec >= 8 ? Kb : Qb);
                dst[((size_t)(b * 8 + h) * 2048 + s) * 64 + nb * 16 + lm] = f2bfu(dacc[nb][r]);
            }
    } else {
#pragma unroll
        for (int nb = 0; nb < 4; nb++)
#pragma unroll
            for (int r = 0; r < 4; r++) {
                int vec = quad * 4 + r;
                int h = vec & 7;
                ushort_t* dst = (vec >= 8 ? Kb : Qb);
                dst[((size_t)(b * 8 + h) * 2048 + s) * 64 + nb * 16 + lm] = trow[vec * 64 + nb * 16 + lm];
            }
    }
}

// ---------- prep: V^T bf16 [bh][65][2048]; masked keys zeroed; row 64 = mask ----------
__global__ __launch_bounds__(256) void prep_vt(const ushort_t* __restrict__ t,
                                               const int* __restrict__ wm,
                                               ushort_t* __restrict__ VtG) {
    __shared__ ushort_t tile[64][72];
    __shared__ float mrow[64];
    int st = blockIdx.x;   // 0..31 (64-key tile)
    int bh = blockIdx.y;   // 0..15
    int b = bh >> 3, h = bh & 7;
    int tid = threadIdx.x;
    if (tid < 64) mrow[tid] = wm[b * 2048 + st * 64 + tid] ? 1.0f : 0.0f;
#pragma unroll
    for (int i = 0; i < 2; i++) {
        int q = i * 256 + tid;          // 0..511
        int r = q >> 3, c8 = (q & 7) * 8;
        uint4 v = *reinterpret_cast<const uint4*>(
            t + (size_t)(b * 2048 + st * 64 + r) * TOUT_ + 1024 + h * 64 + c8);
        *reinterpret_cast<uint4*>(&tile[r][c8]) = v;
    }
    __syncthreads();
#pragma unroll
    for (int i = 0; i < 8; i++) {
        int e = i * 256 + tid;          // 0..2047
        int d = e >> 5, sl = (e & 31) * 2;
        unsigned u0 = (mrow[sl]     != 0.f) ? (unsigned)tile[sl][d]     : 0u;
        unsigned u1 = (mrow[sl + 1] != 0.f) ? (unsigned)tile[sl + 1][d] : 0u;
        *reinterpret_cast<unsigned int*>(VtG + ((size_t)bh * 65 + d) * 2048 + st * 64 + sl) = u0 | (u1 << 16);
    }
    if (tid < 32) {
        int sl = tid * 2;
        unsigned m0 = mrow[sl]     != 0.f ? 0x3F80u : 0u;
        unsigned m1 = mrow[sl + 1] != 0.f ? 0x3F80u : 0u;
        *reinterpret_cast<unsigned int*>(VtG + ((size_t)bh * 65 + 64) * 2048 + st * 64 + sl) = m0 | (m1 << 16);
    }
}

// ==================================================================
// MFMA flash taylor-attention v5: LDS-traffic-minimized.
//  - 128 q per block (4 waves x 32 q): K/V amortized over 2x q rows
//  - K fragments loaded global->reg (L2-hot) - K never touches LDS
//  - swapped QK^T (mfma(K,Q)) so P is written k-contiguous: 8x b64
//    packed writes per wave/tile instead of 32 scalar b16
//  - V double-buffered, 1 barrier per 64-key tile; V[t+1]/K[t+1]
//    prefetched right after the barrier, drained by the next barrier
// Grid (16,8,4) = 512 blocks = 2/CU exact, LDS 33 KB.
// ==================================================================
__global__ __launch_bounds__(256) void tmha_attn_mfma(const ushort_t* __restrict__ Qb,
                                                      const ushort_t* __restrict__ Kb,
                                                      const ushort_t* __restrict__ VtG,
                                                      float* __restrict__ numer,
                                                      float* __restrict__ den) {
    __shared__ __align__(16) ushort_t Vs[2][520 * 8];   // 65 rows x 64 keys, x2 buffers (16.6 KB)
    __shared__ __align__(16) ushort_t Ps[128 * 8 * 8];  // 128 q x 64 keys (16 KB)
    int tid = threadIdx.x;
    int lane = tid & 63;
    int wv = tid >> 6;
    int lm = lane & 15;
    int quad = lane >> 4;
    int qt = blockIdx.x;       // 0..15 (128 q per block)
    int h = blockIdx.y;
    int z = blockIdx.z;
    int b = z >> 1;
    int ks = z & 1;
    int bh = b * 8 + h;

    const ushort_t* Kbh = Kb + (size_t)bh * 2048 * 64;
    const ushort_t* Vbh = VtG + (size_t)bh * 65 * 2048;

    // Q fragments: 2 m-tiles x 2 d-chunks (B-operand of swapped QK^T)
    bf16x8 qf[2][2];
#pragma unroll
    for (int m = 0; m < 2; m++) {
        const ushort_t* qp = Qb + ((size_t)bh * 2048 + qt * 128 + wv * 32 + m * 16 + lm) * 64 + quad * 8;
        qf[m][0] = *reinterpret_cast<const bf16x8*>(qp);
        qf[m][1] = *reinterpret_cast<const bf16x8*>(qp + 32);
    }

    bf16x8 vzero;
    *reinterpret_cast<uint4*>(&vzero) = (uint4){0u, 0u, 0u, 0u};

    floatx4 oacc[2][4];
    floatx4 dacc[2];
#pragma unroll
    for (int m = 0; m < 2; m++) {
        dacc[m] = (floatx4){0.f, 0.f, 0.f, 0.f};
#pragma unroll
        for (int j = 0; j < 4; j++) oacc[m][j] = (floatx4){0.f, 0.f, 0.f, 0.f};
    }

    auto stageV = [&](int buf, int kt) {
#pragma unroll
        for (int t4 = 0; t4 < 2; t4++) {
            int p = (wv * 2 + t4) * 64 + lane;
            int row = p >> 3, cp = p & 7;
            int gc = cp ^ (row & 7);
            const ushort_t* g = Vbh + (size_t)row * 2048 + kt + gc * 8;
            __builtin_amdgcn_global_load_lds((const AS_GLB unsigned int*)g,
                                             (AS_LDS unsigned int*)&Vs[buf][(wv * 2 + t4) * 64 * 8],
                                             16, 0, 0);
        }
        if (tid < 8) {
            const ushort_t* g = Vbh + (size_t)64 * 2048 + kt + tid * 8;
            __builtin_amdgcn_global_load_lds((const AS_GLB unsigned int*)g,
                                             (AS_LDS unsigned int*)&Vs[buf][512 * 8],
                                             16, 0, 0);
        }
    };
    auto loadK = [&](bf16x8 (&kr)[4][2], int kt) {
#pragma unroll
        for (int j = 0; j < 4; j++)
#pragma unroll
            for (int kc = 0; kc < 2; kc++)
                kr[j][kc] = *reinterpret_cast<const bf16x8*>(
                    Kbh + (size_t)(kt + j * 16 + lm) * 64 + (kc * 4 + quad) * 8);
    };

    auto tile = [&](int buf, bf16x8 (&kr)[4][2], bf16x8 (&krn)[4][2], int ktn) {
        __syncthreads();                 // V[t] ready; prev reads of buf^1 done
        stageV(buf ^ 1, ktn);            // prefetch V[t+1]

        // ---- swapped QK^T: D[key][q] ----
        floatx4 sacc[2][4];
#pragma unroll
        for (int m = 0; m < 2; m++)
#pragma unroll
            for (int j = 0; j < 4; j++) sacc[m][j] = (floatx4){0.f, 0.f, 0.f, 0.f};
#pragma unroll
        for (int j = 0; j < 4; j++)
#pragma unroll
            for (int m = 0; m < 2; m++)
#pragma unroll
                for (int kc = 0; kc < 2; kc++)
                    sacc[m][j] = __builtin_amdgcn_mfma_f32_16x16x32_bf16(kr[j][kc], qf[m][kc], sacc[m][j], 0, 0, 0);

        loadK(krn, ktn);                 // prefetch K[t+1] fragments

        // ---- taylor weights -> Ps, k-contiguous b64 packed writes ----
#pragma unroll
        for (int m = 0; m < 2; m++)
#pragma unroll
            for (int j = 0; j < 4; j++) {
                ushort_t o[4];
#pragma unroll
                for (int r = 0; r < 4; r++) {
                    float s = sacc[m][j][r];
                    float wgt = fmaf(s, fmaf(s, 0.0078125f, 0.125f), 1.0f);  // 1 + s/8 + s^2/128
                    o[r] = f2bfu(wgt);
                }
                int row = wv * 32 + m * 16 + lm;          // q row (lane-local)
                int k0 = j * 16 + quad * 4;               // 4 consecutive keys
                int pos = row * 8 + ((k0 >> 3) ^ (row & 7));
                *reinterpret_cast<uint2*>(&Ps[pos * 8 + (k0 & 7)]) = *reinterpret_cast<const uint2*>(o);
            }
        // Ps rows are wave-private: LDS fence only, no cross-wave barrier.
        asm volatile("s_waitcnt lgkmcnt(0)" ::: "memory");
        __builtin_amdgcn_sched_barrier(0);

        // ---- P @ V': O[32 q][64 d] + denominator ----
        bf16x8 pa[2][2];
#pragma unroll
        for (int m = 0; m < 2; m++)
#pragma unroll
            for (int kc = 0; kc < 2; kc++) {
                int row = wv * 32 + m * 16 + lm;
                int c = kc * 4 + quad;
                int pos = row * 8 + (c ^ (row & 7));
                pa[m][kc] = *reinterpret_cast<const bf16x8*>(&Ps[pos * 8]);
            }
#pragma unroll
        for (int j = 0; j < 4; j++) {
            int vrow = j * 16 + lm;
#pragma unroll
            for (int kc = 0; kc < 2; kc++) {
                int c = kc * 4 + quad;
                int vpos = vrow * 8 + (c ^ (vrow & 7));
                bf16x8 vb = *reinterpret_cast<const bf16x8*>(&Vs[buf][vpos * 8]);
#pragma unroll
                for (int m = 0; m < 2; m++)
                    oacc[m][j] = __builtin_amdgcn_mfma_f32_16x16x32_bf16(pa[m][kc], vb, oacc[m][j], 0, 0, 0);
            }
        }
#pragma unroll
        for (int kc = 0; kc < 2; kc++) {
            int c = kc * 4 + quad;
            bf16x8 vb = *reinterpret_cast<const bf16x8*>(&Vs[buf][(512 + c) * 8]);  // mask row 64
            if (lm != 0) vb = vzero;
#pragma unroll
            for (int m = 0; m < 2; m++)
                dacc[m] = __builtin_amdgcn_mfma_f32_16x16x32_bf16(pa[m][kc], vb, dacc[m], 0, 0, 0);
        }
    };

    bf16x8 kA[4][2], kB[4][2];
    int kt0 = ks * 1024;
    stageV(0, kt0);
    loadK(kA, kt0);
#pragma unroll 1
    for (int tt = 0; tt < 8; tt++) {
        int kt = kt0 + tt * 128;
        int kt1 = kt + 64;
        int kt2 = (tt == 7) ? kt0 : kt + 128;   // wrapped prefetch addr (values unused)
        tile(0, kA, kB, kt1);
        tile(1, kB, kA, kt2);
    }

    // ---- epilogue: write split numerator + denominator (fp32) ----
#pragma unroll
    for (int m = 0; m < 2; m++) {
#pragma unroll
        for (int j = 0; j < 4; j++)
#pragma unroll
            for (int r = 0; r < 4; r++) {
                int qrow = b * 2048 + qt * 128 + wv * 32 + m * 16 + quad * 4 + r;
                numer[((size_t)ks * ROWS_ + qrow) * DIM_ + h * 64 + j * 16 + lm] = oacc[m][j][r];
            }
        if (lm == 0) {
#pragma unroll
            for (int r = 0; r < 4; r++) {
                int qrow = b * 2048 + qt * 128 + wv * 32 + m * 16 + quad * 4 + r;
                den[((size_t)ks * ROWS_ + qrow) * 8 + h] = dacc[m][r];
            }
        }
    }
}

// ---------- combine splits: attn = (n0+n1)/(d0+d1), bf16 ----------
__global__ __launch_bounds__(256) void attn_combine(const float* __restrict__ numer,
                                                    const float* __restrict__ den,
                                                    ushort_t* __restrict__ attnAb) {
    int i = blockIdx.x * 256 + threadIdx.x;      // over 4096*128 float4s
    int row = i >> 7;
    int c4 = (i & 127) * 4;
    int h = c4 >> 6;
    float4 n0 = *reinterpret_cast<const float4*>(&numer[(size_t)row * DIM_ + c4]);
    float4 n1 = *reinterpret_cast<const float4*>(&numer[((size_t)ROWS_ + row) * DIM_ + c4]);
    float d = den[(size_t)row * 8 + h] + den[((size_t)ROWS_ + row) * 8 + h];
    float inv = 1.0f / d;
    ushort_t o[4] = {f2bfu((n0.x + n1.x) * inv), f2bfu((n0.y + n1.y) * inv),
                     f2bfu((n0.z + n1.z) * inv), f2bfu((n0.w + n1.w) * inv)};
    *reinterpret_cast<uint2*>(&attnAb[(size_t)row * DIM_ + c4]) = *reinterpret_cast<uint2*>(o);
}

extern "C" void kernel_launch(void* const* d_in, const int* in_sizes, int n_in,
                              void* d_out, int out_size, void* d_ws, size_t ws_size,
                              hipStream_t stream) {
    (void)in_sizes; (void)n_in; (void)out_size; (void)ws_size;
    const float* x    = (const float*)d_in[0];
    const void*  mask = d_in[1];
    const float* rot  = (const float*)d_in[2];
    const float* Wt   = (const float*)d_in[3];
    const float* Wo   = (const float*)d_in[4];

    char* ws = (char*)d_ws;
    int* wmask       = (int*)(ws + 64);                     // 16 KB
    ushort_t* t      = (ushort_t*)(ws + 32768);             // bf16 t: 12,582,912 B (region reserves 25 MB)
    ushort_t* Xb     = (ushort_t*)(ws + 25198592);          //  4,194,304 B
    ushort_t* Wtb    = (ushort_t*)(ws + 29392896);          //  1,572,864 B
    ushort_t* Wob    = (ushort_t*)(ws + 30965760);          //    524,288 B
    ushort_t* Qb     = (ushort_t*)(ws + 31490048);          //  4,194,304 B
    ushort_t* Kb     = (ushort_t*)(ws + 35684352);          //  4,194,304 B
    ushort_t* VtG    = (ushort_t*)(ws + 39878656);          //  4,259,840 B
    ushort_t* attnAb = (ushort_t*)(ws + 44138496);          //  4,194,304 B -> ends 48,332,800
    // split-K attention outputs reuse t's region (t is dead after prep_vt)
    float* numer     = (float*)(ws + 32768);                // 2 * 4096 * 512 * 4 = 16,777,216 B
    float* den       = (float*)(ws + 32768 + 16777216);     // 2 * 4096 * 8 * 4 = 262,144 B

    // mask classify + decode (fused, single block)
    tmha_mask<<<1, 256, 0, stream>>>((const unsigned char*)mask, wmask);

    // bf16 casts (fused: x, Wt, Wo)
    cast3_bf16<<<(XN4_ + WTN4_ + WON4_) / 256, 256, 0, stream>>>(x, Wt, Wo, Xb, Wtb, Wob);

    // gemm1: t = x @ Wt^T, bf16 output (TM=64 -> 768 blocks = 3/CU)
    {
        dim3 grid(TOUT_ / 128, ROWS_ / 64);
        mfma_gemm_bt<64, TOUT_, DIM_, true><<<grid, 256, 0, stream>>>(Xb, Wtb, (void*)t);
    }

    // MFMA rotation + q/k bf16 pack (1 wave per position, no LDS)
    rot_qk_mfma<<<ROWS_ / 4, 256, 0, stream>>>(t, rot, wmask, Qb, Kb);

    // masked V^T + mask-row prep
    {
        dim3 grid(32, 16);
        prep_vt<<<grid, 256, 0, stream>>>(t, wmask, VtG);
    }

    // MFMA flash taylor-attention, split-K (ksplit=2): 512 blocks = 2/CU exact
    {
        dim3 grid(16, 8, 4);
        tmha_attn_mfma<<<grid, 256, 0, stream>>>(Qb, Kb, VtG, numer, den);
    }
    attn_combine<<<(ROWS_ * 128) / 256, 256, 0, stream>>>(numer, den, attnAb);

    // gemm2: out = attn @ Wo^T  (TM=32 -> 512 blocks = 2/CU)
    {
        dim3 grid(DIM_ / 128, ROWS_ / 32);
        mfma_gemm_bt<32, DIM_, DIM_, false><<<grid, 256, 0, stream>>>(attnAb, Wob, d_out);
    }
}

// Round 3
// 193.965 us; speedup vs baseline: 1.0724x; 1.0724x over previous
//
#include <hip/hip_runtime.h>
#include <hip/hip_bf16.h>

// Problem constants
#define B_    2
#define S_    2048
#define DIM_  512
#define H_    8
#define HD_   64
#define TOUT_ 1536   // 2*QK + DIM
#define ROWS_ (B_ * S_)   // 4096

typedef unsigned short ushort_t;
typedef __attribute__((ext_vector_type(8))) __bf16 bf16x8;
typedef __attribute__((ext_vector_type(4))) float floatx4;

#define AS_GLB __attribute__((address_space(1)))
#define AS_LDS __attribute__((address_space(3)))

// ---------- numeric helpers ----------
__device__ __forceinline__ unsigned short f2bfu(float f) {
    unsigned u = __float_as_uint(f);
    unsigned r = (u + 0x7fffu + ((u >> 16) & 1u)) >> 16;
    return (unsigned short)r;
}
__device__ __forceinline__ bf16x8 cvt8(const float* p) {
    float4 a = *reinterpret_cast<const float4*>(p);
    float4 b = *reinterpret_cast<const float4*>(p + 4);
    ushort_t o[8] = {f2bfu(a.x), f2bfu(a.y), f2bfu(a.z), f2bfu(a.w),
                     f2bfu(b.x), f2bfu(b.y), f2bfu(b.z), f2bfu(b.w)};
    return *reinterpret_cast<bf16x8*>(o);
}

// ---------- fused mask classify + decode (single block) ----------
__global__ void tmha_mask(const unsigned char* mb, int* wm) {
    __shared__ int s_bf, s_f, s_u8;
    int tid = threadIdx.x;
    if (tid == 0) { s_bf = 0; s_f = 0; s_u8 = 0; }
    __syncthreads();
    int cbf = 0, cf = 0, cu8 = 0;
    for (int i = tid; i < 4096; i += 256) {
        unsigned char v = mb[i];
        if (v == 0x3F || v == 0x80) {
            cf++;
            if ((i & 3) == 1) cbf++;
        } else if (v != 0 && (i & 3) != 0) {
            cu8++;
        }
    }
    atomicAdd(&s_bf, cbf); atomicAdd(&s_f, cf); atomicAdd(&s_u8, cu8);
    __syncthreads();
    int cls = (s_bf > 0) ? 2 : (s_f > 0) ? 3 : (s_u8 > 0) ? 0 : 1;
    for (int i = tid; i < ROWS_; i += 256) {
        int v;
        if (cls == 0)      v = (mb[i] != 0);
        else if (cls == 1) v = (reinterpret_cast<const int*>(mb)[i] != 0);
        else if (cls == 2) v = ((reinterpret_cast<const unsigned short*>(mb)[i] & 0x7fffu) != 0);
        else               v = ((reinterpret_cast<const unsigned int*>(mb)[i] & 0x7fffffffu) != 0);
        wm[i] = v;
    }
}

// ---------- fused fp32 -> bf16 casts for x, Wt, Wo ----------
#define XN4_  (ROWS_ * DIM_ / 4)                  // 524288
#define WTN4_ (TOUT_ * DIM_ / 4)                  // 196608
#define WON4_ (DIM_ * DIM_ / 4)                   // 65536
__global__ __launch_bounds__(256) void cast3_bf16(const float* __restrict__ x,
                                                  const float* __restrict__ wt,
                                                  const float* __restrict__ wo,
                                                  ushort_t* __restrict__ xb,
                                                  ushort_t* __restrict__ wtb,
                                                  ushort_t* __restrict__ wob) {
    int i = blockIdx.x * 256 + threadIdx.x;
    const float* s; ushort_t* d; int off;
    if (i < XN4_)              { s = x;  d = xb;  off = i; }
    else if (i < XN4_ + WTN4_) { s = wt; d = wtb; off = i - XN4_; }
    else                       { s = wo; d = wob; off = i - XN4_ - WTN4_; }
    float4 v = reinterpret_cast<const float4*>(s)[off];
    ushort_t o[4] = {f2bfu(v.x), f2bfu(v.y), f2bfu(v.z), f2bfu(v.w)};
    reinterpret_cast<uint2*>(d)[off] = *reinterpret_cast<uint2*>(o);
}

// ==================================================================
// MFMA GEMM (proven R5): C[M,N] = A[M,K] @ B[N,K]^T, XOR-swizzled LDS.
// OUT_BF16: epilogue casts to bf16 (used for gemm1 -> t).
// ==================================================================
template <int TM, int N, int K, bool OUT_BF16>
__global__ __launch_bounds__(256) void mfma_gemm_bt(const ushort_t* __restrict__ A,
                                                    const ushort_t* __restrict__ Bm,
                                                    void* __restrict__ Cout) {
    constexpr int FM = (TM + 31) / 32;
    __shared__ __align__(16) ushort_t As[TM * 64];
    __shared__ __align__(16) ushort_t Bs[128 * 64];
    int tid = threadIdx.x;
    int lane = tid & 63;
    int wv = tid >> 6;
    int wm = wv >> 1, wn = wv & 1;
    int quad = lane >> 4;
    int mrow = lane & 15;
    int bx = blockIdx.x;
    int by = blockIdx.y;

    floatx4 acc[FM][4];
#pragma unroll
    for (int i = 0; i < FM; i++)
#pragma unroll
        for (int j = 0; j < 4; j++) acc[i][j] = (floatx4){0.f, 0.f, 0.f, 0.f};

    for (int k0 = 0; k0 < K; k0 += 64) {
#pragma unroll
        for (int t = 0; t < TM / 32; t++) {
            int p = (wv * (TM / 32) + t) * 64 + lane;
            int row = p >> 3, cp = p & 7;
            int gc = cp ^ (row & 7);
            const ushort_t* ga = A + (size_t)(by * TM + row) * K + k0 + gc * 8;
            __builtin_amdgcn_global_load_lds((const AS_GLB unsigned int*)ga,
                                             (AS_LDS unsigned int*)&As[(size_t)(wv * (TM / 32) + t) * 64 * 8],
                                             16, 0, 0);
        }
#pragma unroll
        for (int t = 0; t < 4; t++) {
            int p = (wv * 4 + t) * 64 + lane;
            int row = p >> 3, cp = p & 7;
            int gc = cp ^ (row & 7);
            const ushort_t* gb = Bm + (size_t)(bx * 128 + row) * K + k0 + gc * 8;
            __builtin_amdgcn_global_load_lds((const AS_GLB unsigned int*)gb,
                                             (AS_LDS unsigned int*)&Bs[(size_t)(wv * 4 + t) * 64 * 8],
                                             16, 0, 0);
        }
        __syncthreads();
#pragma unroll
        for (int ks = 0; ks < 64; ks += 32) {
            int c = (ks >> 3) + quad;
            bf16x8 af[FM], bf[4];
#pragma unroll
            for (int i = 0; i < FM; i++) {
                int row = wm * (TM / 2) + i * 16 + mrow;
                int pos = row * 8 + (c ^ (row & 7));
                af[i] = *reinterpret_cast<const bf16x8*>(&As[pos * 8]);
            }
#pragma unroll
            for (int j = 0; j < 4; j++) {
                int row = wn * 64 + j * 16 + mrow;
                int pos = row * 8 + (c ^ (row & 7));
                bf[j] = *reinterpret_cast<const bf16x8*>(&Bs[pos * 8]);
            }
#pragma unroll
            for (int i = 0; i < FM; i++)
#pragma unroll
                for (int j = 0; j < 4; j++)
                    acc[i][j] = __builtin_amdgcn_mfma_f32_16x16x32_bf16(af[i], bf[j], acc[i][j], 0, 0, 0);
        }
        __syncthreads();
    }

    int col0 = bx * 128 + wn * 64 + mrow;
    int row0 = by * TM + wm * (TM / 2) + quad * 4;
    if constexpr (OUT_BF16) {
        ushort_t* C = reinterpret_cast<ushort_t*>(Cout);
#pragma unroll
        for (int i = 0; i < FM; i++)
#pragma unroll
            for (int j = 0; j < 4; j++)
#pragma unroll
                for (int r = 0; r < 4; r++)
                    C[(size_t)(row0 + i * 16 + r) * N + col0 + j * 16] = f2bfu(acc[i][j][r]);
    } else {
        float* C = reinterpret_cast<float*>(Cout);
#pragma unroll
        for (int i = 0; i < FM; i++)
#pragma unroll
            for (int j = 0; j < 4; j++)
#pragma unroll
                for (int r = 0; r < 4; r++)
                    C[(size_t)(row0 + i * 16 + r) * N + col0 + j * 16] = acc[i][j][r];
    }
}

// ==================================================================
// MFMA rotation (proven R6, bf16 t input): per position s,
// out = in @ R_s^T if mask. One wave per s, no LDS, no barrier.
// K output is FRAGMENT-MAJOR: Kb[bh][kb][c][l][e] with
//   kb = s>>4 (16-key block), l = s&15, c = dim>>3, e = dim&7
// so attention's per-fragment global loads are fully coalesced.
// ==================================================================
__global__ __launch_bounds__(256) void rot_qk_mfma(const ushort_t* __restrict__ t,
                                                   const float* __restrict__ rotG,
                                                   const int* __restrict__ wm,
                                                   ushort_t* __restrict__ Qb,
                                                   ushort_t* __restrict__ Kb) {
    int lane = threadIdx.x & 63;
    int wv = threadIdx.x >> 6;
    int row = blockIdx.x * 4 + wv;     // b*2048 + s
    int b = row >> 11, s = row & 2047;
    int lm = lane & 15, quad = lane >> 4;
    const ushort_t* trow = t + (size_t)row * TOUT_;
    int kb = s >> 4, l = s & 15;

    if (wm[row]) {
        bf16x8 af[2];
#pragma unroll
        for (int kc = 0; kc < 2; kc++)
            af[kc] = *reinterpret_cast<const bf16x8*>(trow + lm * 64 + kc * 32 + quad * 8);

        const float* R = rotG + (size_t)row * 4096;
        floatx4 dacc[4];
#pragma unroll
        for (int nb = 0; nb < 4; nb++) dacc[nb] = (floatx4){0.f, 0.f, 0.f, 0.f};
#pragma unroll
        for (int nb = 0; nb < 4; nb++)
#pragma unroll
            for (int kc = 0; kc < 2; kc++) {
                bf16x8 bfr = cvt8(R + (size_t)(nb * 16 + lm) * 64 + kc * 32 + quad * 8);
                dacc[nb] = __builtin_amdgcn_mfma_f32_16x16x32_bf16(af[kc], bfr, dacc[nb], 0, 0, 0);
            }
#pragma unroll
        for (int nb = 0; nb < 4; nb++)
#pragma unroll
            for (int r = 0; r < 4; r++) {
                int vec = quad * 4 + r;
                int hh = vec & 7;
                ushort_t v = f2bfu(dacc[nb][r]);
                if (vec >= 8) {
                    int c = nb * 2 + (lm >> 3), e = lm & 7;
                    Kb[(((size_t)(b * 8 + hh) * 128 + kb) * 8 + c) * 128 + l * 8 + e] = v;
                } else {
                    Qb[((size_t)(b * 8 + hh) * 2048 + s) * 64 + nb * 16 + lm] = v;
                }
            }
    } else {
#pragma unroll
        for (int nb = 0; nb < 4; nb++)
#pragma unroll
            for (int r = 0; r < 4; r++) {
                int vec = quad * 4 + r;
                int hh = vec & 7;
                ushort_t v = trow[vec * 64 + nb * 16 + lm];
                if (vec >= 8) {
                    int c = nb * 2 + (lm >> 3), e = lm & 7;
                    Kb[(((size_t)(b * 8 + hh) * 128 + kb) * 8 + c) * 128 + l * 8 + e] = v;
                } else {
                    Qb[((size_t)(b * 8 + hh) * 2048 + s) * 64 + nb * 16 + lm] = v;
                }
            }
    }
}

// ---------- prep: V^T bf16 [bh][65][2048]; masked keys zeroed; row 64 = mask ----------
__global__ __launch_bounds__(256) void prep_vt(const ushort_t* __restrict__ t,
                                               const int* __restrict__ wm,
                                               ushort_t* __restrict__ VtG) {
    __shared__ ushort_t tile[64][72];
    __shared__ float mrow[64];
    int st = blockIdx.x;   // 0..31 (64-key tile)
    int bh = blockIdx.y;   // 0..15
    int b = bh >> 3, h = bh & 7;
    int tid = threadIdx.x;
    if (tid < 64) mrow[tid] = wm[b * 2048 + st * 64 + tid] ? 1.0f : 0.0f;
#pragma unroll
    for (int i = 0; i < 2; i++) {
        int q = i * 256 + tid;          // 0..511
        int r = q >> 3, c8 = (q & 7) * 8;
        uint4 v = *reinterpret_cast<const uint4*>(
            t + (size_t)(b * 2048 + st * 64 + r) * TOUT_ + 1024 + h * 64 + c8);
        *reinterpret_cast<uint4*>(&tile[r][c8]) = v;
    }
    __syncthreads();
#pragma unroll
    for (int i = 0; i < 8; i++) {
        int e = i * 256 + tid;          // 0..2047
        int d = e >> 5, sl = (e & 31) * 2;
        unsigned u0 = (mrow[sl]     != 0.f) ? (unsigned)tile[sl][d]     : 0u;
        unsigned u1 = (mrow[sl + 1] != 0.f) ? (unsigned)tile[sl + 1][d] : 0u;
        *reinterpret_cast<unsigned int*>(VtG + ((size_t)bh * 65 + d) * 2048 + st * 64 + sl) = u0 | (u1 << 16);
    }
    if (tid < 32) {
        int sl = tid * 2;
        unsigned m0 = mrow[sl]     != 0.f ? 0x3F80u : 0u;
        unsigned m1 = mrow[sl + 1] != 0.f ? 0x3F80u : 0u;
        *reinterpret_cast<unsigned int*>(VtG + ((size_t)bh * 65 + 64) * 2048 + st * 64 + sl) = m0 | (m1 << 16);
    }
}

// ==================================================================
// MFMA flash taylor-attention v6 = v4 structure + targeted fixes:
//  - 64 q/block, 4 waves x 16 q, grid (32,8,4)=1024 blocks, 4/CU
//    co-resident (LDS 24.8 KB), 16 waves/CU  [v5's 2/CU was the bug]
//  - K fragments global->reg from FRAGMENT-MAJOR Kb: 1024 contiguous
//    bytes per wave load (v5's 128B-stride was the bug); K never in LDS
//  - V double-buffered, ONE barrier per 64-key tile; V[t+1]/K[t+1]
//    issued right after the barrier, drained by the next barrier
//  - P path identical to v4 (scalar b16 writes, measured 0 conflicts)
// ==================================================================
__global__ __launch_bounds__(256) void tmha_attn_mfma(const ushort_t* __restrict__ Qb,
                                                      const ushort_t* __restrict__ KbF,
                                                      const ushort_t* __restrict__ VtG,
                                                      float* __restrict__ numer,
                                                      float* __restrict__ den) {
    __shared__ __align__(16) ushort_t Vs[2][520 * 8];   // 65 rows x 64 keys x2 (16.6 KB)
    __shared__ __align__(16) ushort_t Ps[512 * 8];      // 64 q x 64 keys (8 KB)
    int tid = threadIdx.x;
    int lane = tid & 63;
    int wv = tid >> 6;
    int lm = lane & 15;
    int quad = lane >> 4;
    int qt = blockIdx.x;       // 0..31
    int h = blockIdx.y;
    int z = blockIdx.z;
    int b = z >> 1;
    int ks = z & 1;
    int bh = b * 8 + h;

    const ushort_t* Kf  = KbF + (size_t)bh * 128 * 1024;   // [kb][c][l][e]
    const ushort_t* Vbh = VtG + (size_t)bh * 65 * 2048;

    bf16x8 qf[2];
    {
        const ushort_t* qp = Qb + ((size_t)bh * 2048 + qt * 64 + wv * 16 + lm) * 64 + quad * 8;
        qf[0] = *reinterpret_cast<const bf16x8*>(qp);
        qf[1] = *reinterpret_cast<const bf16x8*>(qp + 32);
    }

    bf16x8 vzero;
    *reinterpret_cast<uint4*>(&vzero) = (uint4){0u, 0u, 0u, 0u};

    floatx4 oacc[5];
#pragma unroll
    for (int j = 0; j < 5; j++) oacc[j] = (floatx4){0.f, 0.f, 0.f, 0.f};

    bf16x8 kr[4][2];
    auto loadK = [&](int kt) {
        int kb = kt >> 4;
#pragma unroll
        for (int j = 0; j < 4; j++)
#pragma unroll
            for (int kc = 0; kc < 2; kc++)
                kr[j][kc] = *reinterpret_cast<const bf16x8*>(
                    Kf + (((size_t)(kb + j) * 8 + kc * 4 + quad) * 16 + lm) * 8);
    };
    auto stageV = [&](int buf, int kt) {
#pragma unroll
        for (int t4 = 0; t4 < 2; t4++) {
            int p = (wv * 2 + t4) * 64 + lane;
            int row = p >> 3, cp = p & 7;
            int gc = cp ^ (row & 7);
            const ushort_t* g = Vbh + (size_t)row * 2048 + kt + gc * 8;
            __builtin_amdgcn_global_load_lds((const AS_GLB unsigned int*)g,
                                             (AS_LDS unsigned int*)&Vs[buf][(wv * 2 + t4) * 64 * 8],
                                             16, 0, 0);
        }
        if (tid < 8) {
            const ushort_t* g = Vbh + (size_t)64 * 2048 + kt + tid * 8;
            __builtin_amdgcn_global_load_lds((const AS_GLB unsigned int*)g,
                                             (AS_LDS unsigned int*)&Vs[buf][512 * 8],
                                             16, 0, 0);
        }
    };

    int kt0 = ks * 1024;
    stageV(0, kt0);
    loadK(kt0);
    int buf = 0;
#pragma unroll 1
    for (int tt = 0; tt < 16; tt++) {
        int ktn = (tt == 15) ? kt0 : kt0 + (tt + 1) * 64;
        __syncthreads();              // V[buf] + K regs ready (per-wave vmcnt drain + join)
        stageV(buf ^ 1, ktn);         // prefetch next V into other buffer

        // ---- QK^T: 16 q rows x 64 keys, operands entirely in registers ----
        floatx4 sacc[4];
#pragma unroll
        for (int j = 0; j < 4; j++) sacc[j] = (floatx4){0.f, 0.f, 0.f, 0.f};
#pragma unroll
        for (int j = 0; j < 4; j++)
#pragma unroll
            for (int kc = 0; kc < 2; kc++)
                sacc[j] = __builtin_amdgcn_mfma_f32_16x16x32_bf16(qf[kc], kr[j][kc], sacc[j], 0, 0, 0);

        loadK(ktn);                   // prefetch next K into same regs (WAR, reg-dep ordered)

        // ---- taylor weights -> P (bf16, swizzled, wave-private rows; v4 pattern) ----
#pragma unroll
        for (int j = 0; j < 4; j++)
#pragma unroll
            for (int r = 0; r < 4; r++) {
                float s = sacc[j][r];
                float wgt = fmaf(s, fmaf(s, 0.0078125f, 0.125f), 1.0f);  // 1 + s/8 + s^2/128
                int m = wv * 16 + quad * 4 + r;
                int col = j * 16 + lm;
                int cw = col >> 3;
                int pos = m * 8 + (cw ^ (m & 7));
                Ps[pos * 8 + (col & 7)] = f2bfu(wgt);
            }
        // Ps rows are wave-private: LDS fence only, no cross-wave barrier.
        asm volatile("s_waitcnt lgkmcnt(0)" ::: "memory");
        __builtin_amdgcn_sched_barrier(0);

        // ---- P @ V': O[16 q][64 dims] + denominator (row 64) ----
        int qrow_l = wv * 16 + lm;
        bf16x8 pa[2];
#pragma unroll
        for (int kc = 0; kc < 2; kc++) {
            int c = kc * 4 + quad;
            int ppos = qrow_l * 8 + (c ^ (qrow_l & 7));
            pa[kc] = *reinterpret_cast<const bf16x8*>(&Ps[ppos * 8]);
        }
#pragma unroll
        for (int j = 0; j < 5; j++) {
            int vrow = (j < 4) ? (j * 16 + lm) : 64;
#pragma unroll
            for (int kc = 0; kc < 2; kc++) {
                int c = kc * 4 + quad;
                int vpos = vrow * 8 + (c ^ (vrow & 7));
                bf16x8 vb = *reinterpret_cast<const bf16x8*>(&Vs[buf][vpos * 8]);
                if (j == 4 && lm != 0) vb = vzero;   // pad rows beyond 64 are zero
                oacc[j] = __builtin_amdgcn_mfma_f32_16x16x32_bf16(pa[kc], vb, oacc[j], 0, 0, 0);
            }
        }
        buf ^= 1;
    }

    // ---- epilogue: write split numerator + denominator (fp32) ----
#pragma unroll
    for (int j = 0; j < 4; j++)
#pragma unroll
        for (int r = 0; r < 4; r++) {
            int qrow = b * 2048 + qt * 64 + wv * 16 + quad * 4 + r;
            numer[((size_t)ks * ROWS_ + qrow) * DIM_ + h * 64 + j * 16 + lm] = oacc[j][r];
        }
    if (lm == 0) {
#pragma unroll
        for (int r = 0; r < 4; r++) {
            int qrow = b * 2048 + qt * 64 + wv * 16 + quad * 4 + r;
            den[((size_t)ks * ROWS_ + qrow) * 8 + h] = oacc[4][r];
        }
    }
}

// ---------- combine splits: attn = (n0+n1)/(d0+d1), bf16 ----------
__global__ __launch_bounds__(256) void attn_combine(const float* __restrict__ numer,
                                                    const float* __restrict__ den,
                                                    ushort_t* __restrict__ attnAb) {
    int i = blockIdx.x * 256 + threadIdx.x;      // over 4096*128 float4s
    int row = i >> 7;
    int c4 = (i & 127) * 4;
    int h = c4 >> 6;
    float4 n0 = *reinterpret_cast<const float4*>(&numer[(size_t)row * DIM_ + c4]);
    float4 n1 = *reinterpret_cast<const float4*>(&numer[((size_t)ROWS_ + row) * DIM_ + c4]);
    float d = den[(size_t)row * 8 + h] + den[((size_t)ROWS_ + row) * 8 + h];
    float inv = 1.0f / d;
    ushort_t o[4] = {f2bfu((n0.x + n1.x) * inv), f2bfu((n0.y + n1.y) * inv),
                     f2bfu((n0.z + n1.z) * inv), f2bfu((n0.w + n1.w) * inv)};
    *reinterpret_cast<uint2*>(&attnAb[(size_t)row * DIM_ + c4]) = *reinterpret_cast<uint2*>(o);
}

extern "C" void kernel_launch(void* const* d_in, const int* in_sizes, int n_in,
                              void* d_out, int out_size, void* d_ws, size_t ws_size,
                              hipStream_t stream) {
    (void)in_sizes; (void)n_in; (void)out_size; (void)ws_size;
    const float* x    = (const float*)d_in[0];
    const void*  mask = d_in[1];
    const float* rot  = (const float*)d_in[2];
    const float* Wt   = (const float*)d_in[3];
    const float* Wo   = (const float*)d_in[4];

    char* ws = (char*)d_ws;
    int* wmask       = (int*)(ws + 64);                     // 16 KB
    ushort_t* t      = (ushort_t*)(ws + 32768);             // bf16 t: 12,582,912 B (region reserves 25 MB)
    ushort_t* Xb     = (ushort_t*)(ws + 25198592);          //  4,194,304 B
    ushort_t* Wtb    = (ushort_t*)(ws + 29392896);          //  1,572,864 B
    ushort_t* Wob    = (ushort_t*)(ws + 30965760);          //    524,288 B
    ushort_t* Qb     = (ushort_t*)(ws + 31490048);          //  4,194,304 B
    ushort_t* Kb     = (ushort_t*)(ws + 35684352);          //  4,194,304 B (fragment-major)
    ushort_t* VtG    = (ushort_t*)(ws + 39878656);          //  4,259,840 B
    ushort_t* attnAb = (ushort_t*)(ws + 44138496);          //  4,194,304 B -> ends 48,332,800
    // split-K attention outputs reuse t's region (t is dead after prep_vt)
    float* numer     = (float*)(ws + 32768);                // 2 * 4096 * 512 * 4 = 16,777,216 B
    float* den       = (float*)(ws + 32768 + 16777216);     // 2 * 4096 * 8 * 4 = 262,144 B

    // mask classify + decode (fused, single block)
    tmha_mask<<<1, 256, 0, stream>>>((const unsigned char*)mask, wmask);

    // bf16 casts (fused: x, Wt, Wo)
    cast3_bf16<<<(XN4_ + WTN4_ + WON4_) / 256, 256, 0, stream>>>(x, Wt, Wo, Xb, Wtb, Wob);

    // gemm1: t = x @ Wt^T, bf16 output (TM=64 -> 768 blocks = 3/CU)
    {
        dim3 grid(TOUT_ / 128, ROWS_ / 64);
        mfma_gemm_bt<64, TOUT_, DIM_, true><<<grid, 256, 0, stream>>>(Xb, Wtb, (void*)t);
    }

    // MFMA rotation + q/k bf16 pack (1 wave per position, no LDS)
    rot_qk_mfma<<<ROWS_ / 4, 256, 0, stream>>>(t, rot, wmask, Qb, Kb);

    // masked V^T + mask-row prep
    {
        dim3 grid(32, 16);
        prep_vt<<<grid, 256, 0, stream>>>(t, wmask, VtG);
    }

    // MFMA flash taylor-attention, split-K (ksplit=2): 1024 blocks, 4/CU co-resident
    {
        dim3 grid(32, 8, 4);
        tmha_attn_mfma<<<grid, 256, 0, stream>>>(Qb, Kb, VtG, numer, den);
    }
    attn_combine<<<(ROWS_ * 128) / 256, 256, 0, stream>>>(numer, den, attnAb);

    // gemm2: out = attn @ Wo^T  (TM=32 -> 512 blocks = 2/CU)
    {
        dim3 grid(DIM_ / 128, ROWS_ / 32);
        mfma_gemm_bt<32, DIM_, DIM_, false><<<grid, 256, 0, stream>>>(attnAb, Wob, d_out);
    }
}